// Round 1
// 871.722 us; speedup vs baseline: 1.3167x; 1.3167x over previous
//
#include <hip/hip_runtime.h>

typedef __bf16 bf16;
typedef __bf16 bf16x8 __attribute__((ext_vector_type(8)));
typedef float f32x4 __attribute__((ext_vector_type(4)));

__device__ __forceinline__ void gld_lds16(const bf16* g, bf16* lds_base) {
    __builtin_amdgcn_global_load_lds(
        (const __attribute__((address_space(1))) void*)g,
        (__attribute__((address_space(3))) void*)lds_base, 16, 0, 0);
}

// ---------------------------------------------------------------------------
// Dtype detector: flag=0 if float tensors are bf16, 1 if fp32.
// ---------------------------------------------------------------------------
__global__ void detect_k(const unsigned* __restrict__ rnn, int* __restrict__ flag) {
    const int lane = threadIdx.x;  // 64 threads
    const unsigned w = rnn[lane];
    const int e = (w >> 7) & 0xFF;
    const bool good = (e >= 100 && e <= 130);
    const unsigned long long m = __ballot(good);
    if (lane == 0) *flag = (__popcll(m) >= 48) ? 0 : 1;
}

// ---------------------------------------------------------------------------
// Batched 64x64 tile transpose: in (B,R,C) [dtype per flag] -> out (B,C,R) bf16.
// ---------------------------------------------------------------------------
__global__ __launch_bounds__(256) void transpose_k(const void* __restrict__ in_,
                                                   bf16* __restrict__ out,
                                                   const int* __restrict__ flag,
                                                   int R, int C) {
    __shared__ __align__(16) bf16 t[64][72];
    const int dt = *flag;
    const long boff = (long)blockIdx.z * R * C;
    const int c0 = blockIdx.x * 64, r0 = blockIdx.y * 64;
    const int lr = threadIdx.x >> 2;
    const int lc = (threadIdx.x & 3) * 16;

    bf16x8 v0, v1;
    if (dt) {
        const float* src = (const float*)in_ + boff + (long)(r0 + lr) * C + c0 + lc;
        float4 f0 = ((const float4*)src)[0];
        float4 f1 = ((const float4*)src)[1];
        float4 f2 = ((const float4*)src)[2];
        float4 f3 = ((const float4*)src)[3];
        v0[0]=(bf16)f0.x; v0[1]=(bf16)f0.y; v0[2]=(bf16)f0.z; v0[3]=(bf16)f0.w;
        v0[4]=(bf16)f1.x; v0[5]=(bf16)f1.y; v0[6]=(bf16)f1.z; v0[7]=(bf16)f1.w;
        v1[0]=(bf16)f2.x; v1[1]=(bf16)f2.y; v1[2]=(bf16)f2.z; v1[3]=(bf16)f2.w;
        v1[4]=(bf16)f3.x; v1[5]=(bf16)f3.y; v1[6]=(bf16)f3.z; v1[7]=(bf16)f3.w;
    } else {
        const bf16* src = (const bf16*)in_ + boff + (long)(r0 + lr) * C + c0 + lc;
        v0 = ((const bf16x8*)src)[0];
        v1 = ((const bf16x8*)src)[1];
    }
    *(bf16x8*)(&t[lr][lc])     = v0;
    *(bf16x8*)(&t[lr][lc + 8]) = v1;
    __syncthreads();

    bf16 tmp[16];
#pragma unroll
    for (int k = 0; k < 16; ++k) tmp[k] = t[lc + k][lr];
    bf16* dst = out + boff + (long)(c0 + lr) * R + r0 + lc;
    *(float4*)(dst)     = *(float4*)(&tmp[0]);
    *(float4*)(dst + 8) = *(float4*)(&tmp[8]);
}

// ---------------------------------------------------------------------------
// Shared MFMA helpers: 128x128 tile, BK=64, XOR-swizzled LDS
// (LDS[row][c] = G[row][c^(row&7)], 8-elem chunks). gridDim.x==8 and
// gridDim.y%8==0 required for the XCD swizzle: lin = by*8+bx;
// mb=(lin>>6)*8+(lin&7), nb=(lin>>3)&7 -> the 8 blocks sharing an A-tile
// satisfy lin === mb (mod 8) -> same XCD -> A-tile L2 reuse.
//
// K-loop: double-buffered LDS (2x32KB), ONE barrier per K-step. Stage for
// tile t+1 is issued BEFORE the MFMAs of tile t; the compiler's vmcnt(0)
// drain at __syncthreads then lands after ~(16 ds_read + 32 MFMA) of cover.
// All K here are multiples of 128 -> nt even -> unroll x2 for static buffer
// indices (no scratch).
// ---------------------------------------------------------------------------
__device__ __forceinline__ void mfma_tile(const bf16* As, const bf16* Bs,
                                          int wm, int wn, int quad, int l15,
                                          f32x4 acc[4][4]) {
#pragma unroll
    for (int kk = 0; kk < 2; ++kk) {
        bf16x8 af[4], bff[4];
        const int kc = kk * 4 + quad;
#pragma unroll
        for (int i = 0; i < 4; ++i) {
            const int m = wm * 64 + i * 16 + l15;
            af[i] = *(const bf16x8*)(As + m * 64 + (kc ^ (m & 7)) * 8);
            const int n = wn * 64 + i * 16 + l15;
            bff[i] = *(const bf16x8*)(Bs + n * 64 + (kc ^ (n & 7)) * 8);
        }
#pragma unroll
        for (int i = 0; i < 4; ++i)
#pragma unroll
            for (int j = 0; j < 4; ++j)
                acc[i][j] = __builtin_amdgcn_mfma_f32_16x16x32_bf16(
                    af[i], bff[j], acc[i][j], 0, 0, 0);
    }
}

__device__ __forceinline__ void stageAB(const bf16* a, const bf16* b, int K,
                                        bf16* Asb, bf16* Bsb, int lbase) {
#pragma unroll
    for (int r = 0; r < 4; ++r) {
        gld_lds16(a + (long)(r * 32) * K, Asb + r * 2048 + lbase);
        gld_lds16(b + (long)(r * 32) * K, Bsb + r * 2048 + lbase);
    }
}

__device__ __forceinline__ void stageB(const bf16* b, int K, bf16* Bsb, int lbase) {
#pragma unroll
    for (int r = 0; r < 4; ++r)
        gld_lds16(b + (long)(r * 32) * K, Bsb + r * 2048 + lbase);
}

__device__ __forceinline__ void issueA_f32(const char* Ag4, int K, int k0,
                                           float4 fa[8]) {
#pragma unroll
    for (int r = 0; r < 4; ++r) {
        const float4* pa = (const float4*)(Ag4 + ((long)(r * 32) * K + k0) * 4);
        fa[2 * r]     = pa[0];
        fa[2 * r + 1] = pa[1];
    }
}

__device__ __forceinline__ void writeA_cvt(bf16* Asb, const float4 fa[8], int ldst) {
#pragma unroll
    for (int r = 0; r < 4; ++r) {
        const float4 f0 = fa[2 * r], f1 = fa[2 * r + 1];
        bf16x8 v;
        v[0]=(bf16)f0.x; v[1]=(bf16)f0.y; v[2]=(bf16)f0.z; v[3]=(bf16)f0.w;
        v[4]=(bf16)f1.x; v[5]=(bf16)f1.y; v[6]=(bf16)f1.z; v[7]=(bf16)f1.w;
        *(bf16x8*)(Asb + r * 2048 + ldst) = v;
    }
}

// ---------------------------------------------------------------------------
// Front GEMM: C = bf16(relu(A @ Bt^T + bias)). A (M,K) dtype per flag;
// Bt (N,K) bf16 (ws); bias dtype per flag; C bf16 (ws). grid (8, M/128).
// ---------------------------------------------------------------------------
__global__ __launch_bounds__(256, 2) void gemm_front(const void* __restrict__ A_,
                                                     const bf16* __restrict__ Bt,
                                                     const void* __restrict__ bias_,
                                                     bf16* __restrict__ C,
                                                     const int* __restrict__ flag,
                                                     int M, int N, int K) {
    __shared__ __align__(16) bf16 As[2][128 * 64];
    __shared__ __align__(16) bf16 Bs[2][128 * 64];

    const int dt = *flag;
    const int tid = threadIdx.x, lane = tid & 63, wid = tid >> 6;
    const int wm = wid & 1, wn = wid >> 1;

    const int lin = blockIdx.y * 8 + blockIdx.x;
    const int m0 = ((lin >> 6) * 8 + (lin & 7)) * 128;
    const int n0 = ((lin >> 3) & 7) * 128;

    const int srow = wid * 8 + (lane >> 3);
    const int scol = ((lane & 7) ^ (srow & 7)) * 8;
    const bf16* Bg = Bt + (long)(n0 + srow) * K + scol;
    const int ldst = wid * 512 + lane * 8;   // per-lane A ds_write dst (elems)
    const int lbase = wid * 512;             // wave-uniform async dst base

    f32x4 acc[4][4];
#pragma unroll
    for (int i = 0; i < 4; ++i)
#pragma unroll
        for (int j = 0; j < 4; ++j) acc[i][j] = (f32x4){0.f, 0.f, 0.f, 0.f};

    const int quad = lane >> 4, l15 = lane & 15;
    const int nt = K >> 6;   // even for all shapes used here

    if (dt) {  // fp32 A: reg-stage A (issue-early / convert-late), async B
        const char* Ag4 = (const char*)A_ + ((long)(m0 + srow) * K + scol) * 4;
        float4 fa[8];
        issueA_f32(Ag4, K, 0, fa);
        stageB(Bg, K, Bs[0], lbase);
        writeA_cvt(As[0], fa, ldst);
        __syncthreads();
        int t = 0;
        for (; t < nt - 2; t += 2) {
            issueA_f32(Ag4, K, (t + 1) << 6, fa);
            stageB(Bg + ((t + 1) << 6), K, Bs[1], lbase);
            mfma_tile(As[0], Bs[0], wm, wn, quad, l15, acc);
            writeA_cvt(As[1], fa, ldst);
            __syncthreads();
            issueA_f32(Ag4, K, (t + 2) << 6, fa);
            stageB(Bg + ((t + 2) << 6), K, Bs[0], lbase);
            mfma_tile(As[1], Bs[1], wm, wn, quad, l15, acc);
            writeA_cvt(As[0], fa, ldst);
            __syncthreads();
        }
        issueA_f32(Ag4, K, (nt - 1) << 6, fa);
        stageB(Bg + ((nt - 1) << 6), K, Bs[1], lbase);
        mfma_tile(As[0], Bs[0], wm, wn, quad, l15, acc);
        writeA_cvt(As[1], fa, ldst);
        __syncthreads();
        mfma_tile(As[1], Bs[1], wm, wn, quad, l15, acc);
    } else {   // bf16 A: fully async A and B
        const bf16* Agb = (const bf16*)A_ + (long)(m0 + srow) * K + scol;
        stageAB(Agb, Bg, K, As[0], Bs[0], lbase);
        __syncthreads();
        int t = 0;
        for (; t < nt - 2; t += 2) {
            stageAB(Agb + ((t + 1) << 6), Bg + ((t + 1) << 6), K, As[1], Bs[1], lbase);
            mfma_tile(As[0], Bs[0], wm, wn, quad, l15, acc);
            __syncthreads();
            stageAB(Agb + ((t + 2) << 6), Bg + ((t + 2) << 6), K, As[0], Bs[0], lbase);
            mfma_tile(As[1], Bs[1], wm, wn, quad, l15, acc);
            __syncthreads();
        }
        stageAB(Agb + ((nt - 1) << 6), Bg + ((nt - 1) << 6), K, As[1], Bs[1], lbase);
        mfma_tile(As[0], Bs[0], wm, wn, quad, l15, acc);
        __syncthreads();
        mfma_tile(As[1], Bs[1], wm, wn, quad, l15, acc);
    }

#pragma unroll
    for (int j = 0; j < 4; ++j) {
        const int colg = n0 + wn * 64 + j * 16 + l15;
        const float bj = dt ? ((const float*)bias_)[colg]
                            : (float)((const bf16*)bias_)[colg];
#pragma unroll
        for (int i = 0; i < 4; ++i) {
            const int rowb = m0 + wm * 64 + i * 16 + quad * 4;
#pragma unroll
            for (int r = 0; r < 4; ++r) {
                float v = acc[i][j][r] + bj;
                v = v > 0.f ? v : 0.f;
                C[(long)(rowb + r) * N + colg] = (bf16)v;
            }
        }
    }
}

// ---------------------------------------------------------------------------
// Combined expert GEMM: all 7 (group,expert) pairs in one launch for
// occupancy. M=2048, N=1024 for all; K and A vary per z. Fused layer-2
// epilogue: atomicAdd S[m][o] += sum_n relu(acc+bias[n]) * W2[n][o].
// ---------------------------------------------------------------------------
struct ExpDescs {
    const void* A[7];
    const bf16* Bt[7];
    const void* biasB[7];
    const void* w2B[7];
    float* S[7];
    long biasEoff[7];
    long w2Eoff[7];
    int K[7];
    int adt[7];   // 1: A has input dtype (per flag); 0: A is ws bf16
};

__global__ __launch_bounds__(256, 2) void gemm_expert(ExpDescs d,
                                                      const int* __restrict__ flag) {
    __shared__ __align__(16) bf16 As[2][128 * 64];
    __shared__ __align__(16) bf16 Bs[2][128 * 64];

    const int z = blockIdx.z;
    const int dt = *flag;
    const int adt = d.adt[z] ? dt : 0;
    const int K = d.K[z];
    const void* A_ = d.A[z];
    const bf16* Bt = d.Bt[z];

    const int tid = threadIdx.x, lane = tid & 63, wid = tid >> 6;
    const int wm = wid & 1, wn = wid >> 1;

    const int lin = blockIdx.y * 8 + blockIdx.x;
    const int m0 = ((lin >> 6) * 8 + (lin & 7)) * 128;
    const int n0 = ((lin >> 3) & 7) * 128;

    const int srow = wid * 8 + (lane >> 3);
    const int scol = ((lane & 7) ^ (srow & 7)) * 8;
    const bf16* Bg = Bt + (long)(n0 + srow) * K + scol;
    const int ldst = wid * 512 + lane * 8;
    const int lbase = wid * 512;

    f32x4 acc[4][4];
#pragma unroll
    for (int i = 0; i < 4; ++i)
#pragma unroll
        for (int j = 0; j < 4; ++j) acc[i][j] = (f32x4){0.f, 0.f, 0.f, 0.f};

    const int quad = lane >> 4, l15 = lane & 15;
    const int nt = K >> 6;   // even for all shapes used here

    if (adt) {  // fp32 A: reg-stage A (issue-early / convert-late), async B
        const char* Ag4 = (const char*)A_ + ((long)(m0 + srow) * K + scol) * 4;
        float4 fa[8];
        issueA_f32(Ag4, K, 0, fa);
        stageB(Bg, K, Bs[0], lbase);
        writeA_cvt(As[0], fa, ldst);
        __syncthreads();
        int t = 0;
        for (; t < nt - 2; t += 2) {
            issueA_f32(Ag4, K, (t + 1) << 6, fa);
            stageB(Bg + ((t + 1) << 6), K, Bs[1], lbase);
            mfma_tile(As[0], Bs[0], wm, wn, quad, l15, acc);
            writeA_cvt(As[1], fa, ldst);
            __syncthreads();
            issueA_f32(Ag4, K, (t + 2) << 6, fa);
            stageB(Bg + ((t + 2) << 6), K, Bs[0], lbase);
            mfma_tile(As[1], Bs[1], wm, wn, quad, l15, acc);
            writeA_cvt(As[0], fa, ldst);
            __syncthreads();
        }
        issueA_f32(Ag4, K, (nt - 1) << 6, fa);
        stageB(Bg + ((nt - 1) << 6), K, Bs[1], lbase);
        mfma_tile(As[0], Bs[0], wm, wn, quad, l15, acc);
        writeA_cvt(As[1], fa, ldst);
        __syncthreads();
        mfma_tile(As[1], Bs[1], wm, wn, quad, l15, acc);
    } else {    // async A and B (both bf16)
        const bf16* Agb = (const bf16*)A_ + (long)(m0 + srow) * K + scol;
        stageAB(Agb, Bg, K, As[0], Bs[0], lbase);
        __syncthreads();
        int t = 0;
        for (; t < nt - 2; t += 2) {
            stageAB(Agb + ((t + 1) << 6), Bg + ((t + 1) << 6), K, As[1], Bs[1], lbase);
            mfma_tile(As[0], Bs[0], wm, wn, quad, l15, acc);
            __syncthreads();
            stageAB(Agb + ((t + 2) << 6), Bg + ((t + 2) << 6), K, As[0], Bs[0], lbase);
            mfma_tile(As[1], Bs[1], wm, wn, quad, l15, acc);
            __syncthreads();
        }
        stageAB(Agb + ((nt - 1) << 6), Bg + ((nt - 1) << 6), K, As[1], Bs[1], lbase);
        mfma_tile(As[0], Bs[0], wm, wn, quad, l15, acc);
        __syncthreads();
        mfma_tile(As[1], Bs[1], wm, wn, quad, l15, acc);
    }

    // fused layer-2 epilogue
    const long besz = dt ? 4 : 2;
    const char* bias_b = (const char*)d.biasB[z] + d.biasEoff[z] * besz;
    const char* w2_b   = (const char*)d.w2B[z] + d.w2Eoff[z] * besz;
    float* S = d.S[z];

    float bj[4], w2f[4][2];
#pragma unroll
    for (int j = 0; j < 4; ++j) {
        const int colg = n0 + wn * 64 + j * 16 + l15;
        if (dt) {
            bj[j] = ((const float*)bias_b)[colg];
            w2f[j][0] = ((const float*)w2_b)[colg * 2 + 0];
            w2f[j][1] = ((const float*)w2_b)[colg * 2 + 1];
        } else {
            bj[j] = (float)((const bf16*)bias_b)[colg];
            w2f[j][0] = (float)((const bf16*)w2_b)[colg * 2 + 0];
            w2f[j][1] = (float)((const bf16*)w2_b)[colg * 2 + 1];
        }
    }
#pragma unroll
    for (int i = 0; i < 4; ++i) {
#pragma unroll
        for (int r = 0; r < 4; ++r) {
            float s0 = 0.f, s1 = 0.f;
#pragma unroll
            for (int j = 0; j < 4; ++j) {
                float h = acc[i][j][r] + bj[j];
                h = h > 0.f ? h : 0.f;
                s0 += h * w2f[j][0];
                s1 += h * w2f[j][1];
            }
#pragma unroll
            for (int msk = 1; msk < 16; msk <<= 1) {
                s0 += __shfl_xor(s0, msk);
                s1 += __shfl_xor(s1, msk);
            }
            if (l15 == 0) {
                const int rowg = m0 + wm * 64 + i * 16 + quad * 4 + r;
                atomicAdd(&S[rowg * 2 + 0], s0);
                atomicAdd(&S[rowg * 2 + 1], s1);
            }
        }
    }
}

// ---------------------------------------------------------------------------
// x_dist[n,0:1024] = hd[3n]*hd[3n+1]; x_dist[n,1024:2048] = hd[3n+1]*hd[3n+2]
// ---------------------------------------------------------------------------
__global__ __launch_bounds__(256) void pairprod_k(const bf16* __restrict__ hd,
                                                  bf16* __restrict__ xd) {
    const int idx = blockIdx.x * 256 + threadIdx.x;  // 524288 total
    const int n = idx >> 8;
    const int c8 = (idx & 255) << 3;
    const bf16* p;
    if (c8 < 1024) p = hd + (long)(3 * n) * 1024 + c8;
    else           p = hd + (long)(3 * n + 1) * 1024 + (c8 - 1024);
    const bf16* q = p + 1024;
    bf16x8 a = *(const bf16x8*)p, b = *(const bf16x8*)q;
    bf16x8 o;
#pragma unroll
    for (int k = 0; k < 8; ++k) o[k] = (bf16)((float)a[k] * (float)b[k]);
    *(bf16x8*)(xd + (long)n * 2048 + c8) = o;
}

// ---------------------------------------------------------------------------
// out[(g*2048+n)*2+o] = S[g][eid][n][o] + b2[g][eid][o], dtype per flag.
// ---------------------------------------------------------------------------
__global__ __launch_bounds__(256) void finalize_k(const float* __restrict__ S,
        const int* __restrict__ rnn_eid, const int* __restrict__ room_eid,
        const int* __restrict__ dist_eid, const void* __restrict__ b2_rnn,
        const void* __restrict__ b2_room, const void* __restrict__ b2_dist,
        const int* __restrict__ flag, void* __restrict__ out) {
    const int idx = blockIdx.x * 256 + threadIdx.x;
    if (idx >= 12288) return;
    const int dt = *flag;
    const int o = idx & 1;
    const int row = idx >> 1;
    const int g = row >> 11;
    const int n = row & 2047;
    float v;
    if (g == 0) {
        int e = rnn_eid[n]; e = e < 0 ? 0 : (e > 2 ? 2 : e);
        v = S[e * 4096 + n * 2 + o] +
            (dt ? ((const float*)b2_rnn)[e * 2 + o]
                : (float)((const bf16*)b2_rnn)[e * 2 + o]);
    } else if (g == 1) {
        int e = room_eid[n]; e = e < 0 ? 0 : (e > 1 ? 1 : e);
        v = S[12288 + e * 4096 + n * 2 + o] +
            (dt ? ((const float*)b2_room)[e * 2 + o]
                : (float)((const bf16*)b2_room)[e * 2 + o]);
    } else {
        int e = dist_eid[n]; e = e < 0 ? 0 : (e > 1 ? 1 : e);
        v = S[20480 + e * 4096 + n * 2 + o] +
            (dt ? ((const float*)b2_dist)[e * 2 + o]
                : (float)((const bf16*)b2_dist)[e * 2 + o]);
    }
    if (dt) ((float*)out)[idx] = v;
    else    ((bf16*)out)[idx] = (bf16)v;
}

extern "C" void kernel_launch(void* const* d_in, const int* in_sizes, int n_in,
                              void* d_out, int out_size, void* d_ws, size_t ws_size,
                              hipStream_t stream) {
    const void* rnn_feats = d_in[0];
    const void* cube      = d_in[1];
    const void* ego       = d_in[2];
    const int* rnn_eid    = (const int*)d_in[3];
    const int* room_eid   = (const int*)d_in[4];
    const int* dist_eid   = (const int*)d_in[5];
    const void* Wc        = d_in[6];
    const void* bc        = d_in[7];
    const void* Wd        = d_in[8];
    const void* bd        = d_in[9];
    const void* W1_rnn    = d_in[10];
    const void* b1_rnn    = d_in[11];
    const void* W2_rnn    = d_in[12];
    const void* b2_rnn    = d_in[13];
    const void* W1_room   = d_in[14];
    const void* b1_room   = d_in[15];
    const void* W2_room   = d_in[16];
    const void* b2_room   = d_in[17];
    const void* W1_dist   = d_in[18];
    const void* b1_dist   = d_in[19];
    const void* W2_dist   = d_in[20];
    const void* b2_dist   = d_in[21];

    char* ws = (char*)d_ws;
    float* S     = (float*)ws;                    // 28672 fp32 = 114688 B
    int* flag    = (int*)(ws + 114688);           // 4 B (pad to 256)
    bf16* WcT    = (bf16*)(ws + 114944);          // 1024x3200
    bf16* WdT    = (bf16*)(ws + 6668544);         // 1024x3712
    bf16* WrnnT  = (bf16*)(ws + 14270720);        // 3x1024x1024
    bf16* WroomT = (bf16*)(ws + 20562176);        // 2x1024x8192
    bf16* WdistT = (bf16*)(ws + 54116608);        // 2x1024x2048
    bf16* hc     = (bf16*)(ws + 62505216);        // 16384x1024
    bf16* hd     = (bf16*)(ws + 96059648);        // 6144x1024
    bf16* xd     = (bf16*)(ws + 108642560);       // 2048x2048

    detect_k<<<1, 64, 0, stream>>>((const unsigned*)rnn_feats, flag);
    hipMemsetAsync(S, 0, 114688, stream);

    transpose_k<<<dim3(16, 50, 1),  256, 0, stream>>>(Wc,      WcT,    flag, 3200, 1024);
    transpose_k<<<dim3(16, 58, 1),  256, 0, stream>>>(Wd,      WdT,    flag, 3712, 1024);
    transpose_k<<<dim3(16, 16, 3),  256, 0, stream>>>(W1_rnn,  WrnnT,  flag, 1024, 1024);
    transpose_k<<<dim3(16, 128, 2), 256, 0, stream>>>(W1_room, WroomT, flag, 8192, 1024);
    transpose_k<<<dim3(16, 32, 2),  256, 0, stream>>>(W1_dist, WdistT, flag, 2048, 1024);

    // hc = relu(cube @ Wc + bc)   (16384x1024)
    gemm_front<<<dim3(8, 128), 256, 0, stream>>>(cube, WcT, bc, hc, flag,
                                                 16384, 1024, 3200);
    // hd = relu(ego @ Wd + bd)    (6144x1024)
    gemm_front<<<dim3(8, 48), 256, 0, stream>>>(ego, WdT, bd, hd, flag,
                                                6144, 1024, 3712);
    pairprod_k<<<2048, 256, 0, stream>>>(hd, xd);

    // all 7 expert GEMMs (layer1 + fused layer2 -> S) in one launch.
    // Longest-K experts first (z=0,1 room) for LPT-style backfill.
    ExpDescs D;
    for (int e = 0; e < 2; ++e) {
        const int z = e;
        D.A[z] = hc;                   D.Bt[z] = WroomT + (long)e * 1024 * 8192;
        D.biasB[z] = b1_room;          D.biasEoff[z] = (long)e * 1024;
        D.w2B[z] = W2_room;            D.w2Eoff[z] = (long)e * 2048;
        D.S[z] = S + 12288 + e * 4096; D.K[z] = 8192;  D.adt[z] = 0;
    }
    for (int e = 0; e < 2; ++e) {
        const int z = 2 + e;
        D.A[z] = xd;                   D.Bt[z] = WdistT + (long)e * 1024 * 2048;
        D.biasB[z] = b1_dist;          D.biasEoff[z] = (long)e * 1024;
        D.w2B[z] = W2_dist;            D.w2Eoff[z] = (long)e * 2048;
        D.S[z] = S + 20480 + e * 4096; D.K[z] = 2048;  D.adt[z] = 0;
    }
    for (int e = 0; e < 3; ++e) {
        const int z = 4 + e;
        D.A[z] = rnn_feats;            D.Bt[z] = WrnnT + (long)e * 1024 * 1024;
        D.biasB[z] = b1_rnn;           D.biasEoff[z] = (long)e * 1024;
        D.w2B[z] = W2_rnn;             D.w2Eoff[z] = (long)e * 2048;
        D.S[z] = S + e * 4096;         D.K[z] = 1024;  D.adt[z] = 1;
    }
    gemm_expert<<<dim3(8, 16, 7), 256, 0, stream>>>(D, flag);

    finalize_k<<<48, 256, 0, stream>>>(S, rnn_eid, room_eid, dist_eid,
                                       b2_rnn, b2_room, b2_dist, flag, d_out);
}